// Round 1
// baseline (437.923 us; speedup 1.0000x reference)
//
#include <hip/hip_runtime.h>

#define BS 128
#define NR 3
#define CD 64
#define CG 3
#define CH 256
#define HW 1024   // 32*32

// ---------------------------------------------------------------------------
// Kernel 1: per-(b,n,pixel) fused  s = sigmoid(W3 @ relu(W1 @ [d;g] + b1) + b3)
// One pixel per thread; x[67] in VGPRs; W1/b1/W3 read at wave-uniform
// addresses -> scalar loads, inner loop is v_fmac_f32 with SGPR operand.
// ---------------------------------------------------------------------------
__global__ __launch_bounds__(256) void score_kernel(
    const float* __restrict__ data, const float* __restrict__ gt,
    const float* __restrict__ W1, const float* __restrict__ b1,
    const float* __restrict__ W3, const float* __restrict__ b3,
    float* __restrict__ s_out)
{
    const int bn  = blockIdx.x >> 2;                    // 0..383  (b*NR+n)
    const int pix = ((blockIdx.x & 3) << 8) + threadIdx.x;  // 0..1023
    const int b   = bn / NR;

    // load the 64 data channels for this pixel (coalesced across threads)
    float x[CD];
    const float* dptr = data + (size_t)bn * CD * HW + pix;
#pragma unroll
    for (int c = 0; c < CD; ++c) x[c] = dptr[c * HW];

    const float g0 = gt[(b * CG + 0) * HW + pix];
    const float g1 = gt[(b * CG + 1) * HW + pix];
    const float g2 = gt[(b * CG + 2) * HW + pix];

    float acc = b3[0];
#pragma unroll 2
    for (int o = 0; o < CH; ++o) {
        const float* w1r = W1 + o * (CD + CG);
        float h = b1[o];
#pragma unroll
        for (int c = 0; c < CD; ++c) h = fmaf(w1r[c], x[c], h);
        h = fmaf(w1r[CD + 0], g0, h);
        h = fmaf(w1r[CD + 1], g1, h);
        h = fmaf(w1r[CD + 2], g2, h);
        h = fmaxf(h, 0.0f);
        acc = fmaf(W3[o], h, acc);
    }
    const float s = 1.0f / (1.0f + __expf(-acc));
    s_out[bn * HW + pix] = s;
}

// ---------------------------------------------------------------------------
// Kernel 2: w = s / sum_n(s);  z = sum_n d*w.  Fully coalesced streaming.
// ---------------------------------------------------------------------------
__global__ __launch_bounds__(256) void combine_kernel(
    const float* __restrict__ data, const float* __restrict__ s_in,
    float* __restrict__ out)
{
    const int b   = blockIdx.x >> 2;                    // 0..127
    const int pix = ((blockIdx.x & 3) << 8) + threadIdx.x;

    const float s0 = s_in[(b * NR + 0) * HW + pix];
    const float s1 = s_in[(b * NR + 1) * HW + pix];
    const float s2 = s_in[(b * NR + 2) * HW + pix];
    const float inv = 1.0f / (s0 + s1 + s2);
    const float w0 = s0 * inv, w1 = s1 * inv, w2 = s2 * inv;

    // w output lives after z in the flat concat
    float* wout = out + (size_t)BS * CD * HW;
    wout[(b * NR + 0) * HW + pix] = w0;
    wout[(b * NR + 1) * HW + pix] = w1;
    wout[(b * NR + 2) * HW + pix] = w2;

    const float* d0 = data + (size_t)(b * NR + 0) * CD * HW + pix;
    const float* d1 = data + (size_t)(b * NR + 1) * CD * HW + pix;
    const float* d2 = data + (size_t)(b * NR + 2) * CD * HW + pix;
    float* zout = out + (size_t)b * CD * HW + pix;
#pragma unroll 4
    for (int c = 0; c < CD; ++c) {
        zout[c * HW] = d0[c * HW] * w0 + d1[c * HW] * w1 + d2[c * HW] * w2;
    }
}

extern "C" void kernel_launch(void* const* d_in, const int* in_sizes, int n_in,
                              void* d_out, int out_size, void* d_ws, size_t ws_size,
                              hipStream_t stream)
{
    const float* data = (const float*)d_in[0];
    const float* gt   = (const float*)d_in[1];
    const float* W1   = (const float*)d_in[2];
    const float* b1   = (const float*)d_in[3];
    const float* W3   = (const float*)d_in[4];
    const float* b3   = (const float*)d_in[5];
    float* out   = (float*)d_out;
    float* s_buf = (float*)d_ws;   // BS*NR*HW floats = 1.5 MB

    score_kernel<<<BS * NR * 4, 256, 0, stream>>>(data, gt, W1, b1, W3, b3, s_buf);
    combine_kernel<<<BS * 4, 256, 0, stream>>>(data, s_buf, out);
}

// Round 2
// 230.441 us; speedup vs baseline: 1.9004x; 1.9004x over previous
//
#include <hip/hip_runtime.h>
#include <hip/hip_bf16.h>

#define BS 128
#define NR 3
#define CD 64
#define CG 3
#define CH 256
#define HW 1024   // 32*32
#define K_IN 67   // CD + CG
#define KP 96     // K padded to multiple of 32
#define KB 12     // KP/8 : 16-byte k-blocks
#define P 128     // pixels per block (score kernel)

typedef __attribute__((ext_vector_type(8))) short bf16x8;
typedef __attribute__((ext_vector_type(4))) float f32x4;

static __device__ __forceinline__ short f2bf(float x) {
    union { __hip_bfloat16 b; short s; } c;
    c.b = __float2bfloat16(x);
    return c.s;
}

// ---------------------------------------------------------------------------
// Kernel 1: MFMA-fused  s = sigmoid(W3 @ relu(W1 @ [d;g] + b1) + b3)
// Block = one (bn, 128-pixel tile). 4 waves, each owns 64 hidden channels.
// x staged in LDS as bf16 [kb][pix][8] (contiguous 16B chunks, conflict-free).
// W1 fragments live in VGPRs; f1 is never materialized.
// MFMA 16x16x32 bf16: A lane: row=l&15, k=8*(l>>4)+j (contiguous-8, m92/m97
// ref-checked); C: col=l&15, row=(l>>4)*4+reg (m89).
// ---------------------------------------------------------------------------
__global__ __launch_bounds__(256) void score_kernel(
    const float* __restrict__ data, const float* __restrict__ gt,
    const float* __restrict__ W1, const float* __restrict__ b1,
    const float* __restrict__ W3, const float* __restrict__ b3,
    float* __restrict__ s_out)
{
    __shared__ short xls[KB * P * 8];   // 24 KB
    __shared__ float p_lds[4][P];       // 2 KB

    const int tid  = threadIdx.x;
    const int lane = tid & 63;
    const int wave = tid >> 6;
    const int bn   = blockIdx.x >> 3;          // 0..383
    const int pt0  = (blockIdx.x & 7) * P;     // pixel tile base
    const int b    = bn / NR;

    // ---- stage x = [data(64) ; gt(3) ; zeros] as bf16 into LDS ----
    {
        const int n  = tid & (P - 1);
        const int tt = tid >> 7;               // 0: kb 0..5, 1: kb 6..11
        const int gp = pt0 + n;
        const float* dbase = data + (size_t)bn * (CD * HW) + gp;
#pragma unroll
        for (int i = 0; i < 6; ++i) {
            const int kb = tt * 6 + i;
            bf16x8 v;
#pragma unroll
            for (int j = 0; j < 8; ++j) {
                const int k = kb * 8 + j;
                float val = 0.f;
                if (k < CD)            val = dbase[(size_t)k * HW];
                else if (k < CD + CG)  val = gt[((size_t)b * CG + (k - CD)) * HW + gp];
                v[j] = f2bf(val);
            }
            *(bf16x8*)&xls[(kb * P + n) * 8] = v;
        }
    }

    // ---- per-wave W1 fragments (hidden rows wave*64 .. +64) + b1 folded? ----
    // b1 handled by adding b1 row via W3-dot epilogue? No: fold b1 into acc
    // via an extra K column is not available; instead add b1 before relu.
    const int col = lane & 15;   // A row / B,C col
    const int kq  = lane >> 4;   // k quarter
    bf16x8 afrag[4][3];
#pragma unroll
    for (int mt = 0; mt < 4; ++mt) {
        const int m = wave * 64 + mt * 16 + col;
#pragma unroll
        for (int t = 0; t < 3; ++t) {
            const int k0 = t * 32 + kq * 8;
            bf16x8 v;
#pragma unroll
            for (int j = 0; j < 8; ++j) {
                const int k = k0 + j;
                v[j] = f2bf(k < K_IN ? W1[m * K_IN + k] : 0.f);
            }
            afrag[mt][t] = v;
        }
    }
    // per-lane W3 and b1 values for the C rows this lane owns
    float w3v[4][4], b1v[4][4];
#pragma unroll
    for (int mt = 0; mt < 4; ++mt)
#pragma unroll
        for (int r = 0; r < 4; ++r) {
            const int m = wave * 64 + mt * 16 + kq * 4 + r;
            w3v[mt][r] = W3[m];
            b1v[mt][r] = b1[m];
        }

    __syncthreads();

    // ---- 8 pixel sub-tiles of 16 ----
#pragma unroll
    for (int pt = 0; pt < 8; ++pt) {
        const int pn0 = pt * 16;
        bf16x8 bfrag[3];
#pragma unroll
        for (int t = 0; t < 3; ++t)
            bfrag[t] = *(const bf16x8*)&xls[(((4 * t + kq) * P) + pn0 + col) * 8];

        f32x4 acc[4];
#pragma unroll
        for (int mt = 0; mt < 4; ++mt) acc[mt] = (f32x4){0.f, 0.f, 0.f, 0.f};
#pragma unroll
        for (int t = 0; t < 3; ++t)
#pragma unroll
            for (int mt = 0; mt < 4; ++mt)
                acc[mt] = __builtin_amdgcn_mfma_f32_16x16x32_bf16(
                    afrag[mt][t], bfrag[t], acc[mt], 0, 0, 0);

        float partial = 0.f;
#pragma unroll
        for (int mt = 0; mt < 4; ++mt)
#pragma unroll
            for (int r = 0; r < 4; ++r)
                partial += w3v[mt][r] * fmaxf(acc[mt][r] + b1v[mt][r], 0.f);

        partial += __shfl_xor(partial, 16);
        partial += __shfl_xor(partial, 32);
        if (lane < 16) p_lds[wave][pn0 + lane] = partial;
    }

    __syncthreads();
    if (tid < P) {
        const float t = p_lds[0][tid] + p_lds[1][tid] + p_lds[2][tid]
                      + p_lds[3][tid] + b3[0];
        s_out[(size_t)bn * HW + pt0 + tid] = 1.f / (1.f + __expf(-t));
    }
}

// ---------------------------------------------------------------------------
// Kernel 2: w = s / sum_n(s);  z = sum_n d*w.  float4 streaming, 2048 blocks.
// ---------------------------------------------------------------------------
__global__ __launch_bounds__(256) void combine_kernel(
    const float* __restrict__ data, const float* __restrict__ s_in,
    float* __restrict__ out)
{
    const int b  = blockIdx.x >> 4;   // 0..127
    const int cc = blockIdx.x & 15;   // channel chunk (4 channels)
    const int p4 = threadIdx.x;       // float4 pixel index, 256 = 1024 px

    const float4 s0 = *(const float4*)(s_in + (size_t)(b * NR + 0) * HW + 4 * p4);
    const float4 s1 = *(const float4*)(s_in + (size_t)(b * NR + 1) * HW + 4 * p4);
    const float4 s2 = *(const float4*)(s_in + (size_t)(b * NR + 2) * HW + 4 * p4);

    float4 w0, w1, w2;
#define NORM(f) { const float inv = 1.f / (s0.f + s1.f + s2.f); \
                  w0.f = s0.f * inv; w1.f = s1.f * inv; w2.f = s2.f * inv; }
    NORM(x) NORM(y) NORM(z) NORM(w)
#undef NORM

    if (cc == 0) {
        float* wout = out + (size_t)BS * CD * HW;
        *(float4*)(wout + (size_t)(b * NR + 0) * HW + 4 * p4) = w0;
        *(float4*)(wout + (size_t)(b * NR + 1) * HW + 4 * p4) = w1;
        *(float4*)(wout + (size_t)(b * NR + 2) * HW + 4 * p4) = w2;
    }

    const size_t dbase = (size_t)b * NR * CD * HW + 4 * p4;
#pragma unroll
    for (int i = 0; i < 4; ++i) {
        const int c = cc * 4 + i;
        const float4 d0 = *(const float4*)(data + dbase + (size_t)(0 * CD + c) * HW);
        const float4 d1 = *(const float4*)(data + dbase + (size_t)(1 * CD + c) * HW);
        const float4 d2 = *(const float4*)(data + dbase + (size_t)(2 * CD + c) * HW);
        float4 z;
        z.x = d0.x * w0.x + d1.x * w1.x + d2.x * w2.x;
        z.y = d0.y * w0.y + d1.y * w1.y + d2.y * w2.y;
        z.z = d0.z * w0.z + d1.z * w1.z + d2.z * w2.z;
        z.w = d0.w * w0.w + d1.w * w1.w + d2.w * w2.w;
        *(float4*)(out + ((size_t)b * CD + c) * HW + 4 * p4) = z;
    }
}

extern "C" void kernel_launch(void* const* d_in, const int* in_sizes, int n_in,
                              void* d_out, int out_size, void* d_ws, size_t ws_size,
                              hipStream_t stream)
{
    const float* data = (const float*)d_in[0];
    const float* gt   = (const float*)d_in[1];
    const float* W1   = (const float*)d_in[2];
    const float* b1   = (const float*)d_in[3];
    const float* W3   = (const float*)d_in[4];
    const float* b3   = (const float*)d_in[5];
    float* out   = (float*)d_out;
    float* s_buf = (float*)d_ws;   // BS*NR*HW floats = 1.5 MB

    score_kernel<<<BS * NR * (HW / P), 256, 0, stream>>>(data, gt, W1, b1, W3, b3, s_buf);
    combine_kernel<<<BS * 16, 256, 0, stream>>>(data, s_buf, out);
}

// Round 3
// 216.381 us; speedup vs baseline: 2.0239x; 1.0650x over previous
//
#include <hip/hip_runtime.h>
#include <hip/hip_bf16.h>

#define BS 128
#define NR 3
#define CD 64
#define CG 3
#define CH 256
#define HW 1024   // 32*32
#define K_IN 67   // CD + CG; k==67 is the folded-bias constant-1 column
#define NKB 12    // 96 padded k / 8 per 16B chunk
#define P 64      // pixels per block

typedef __attribute__((ext_vector_type(8))) short bf16x8;
typedef __attribute__((ext_vector_type(4))) float f32x4;

static __device__ __forceinline__ short f2bf(float x) {
    union { __hip_bfloat16 b; short s; } c;
    c.b = __float2bfloat16(x);
    return c.s;
}
static __device__ __forceinline__ float bf2f(short s) {
    union { unsigned u; float f; } c;
    c.u = (unsigned)(unsigned short)s << 16;
    return c.f;
}

// ---------------------------------------------------------------------------
// prep: pack W1 (with b1 folded at k=67) into MFMA-A fragment order, bf16.
// frag layout: w1f[((mt*3 + t)*64 + lane)*8 + j] where A row = mt*16+(lane&15),
// k = t*32 + (lane>>4)*8 + j.  49 KB into d_ws. Runs every launch (tiny).
// ---------------------------------------------------------------------------
__global__ __launch_bounds__(256) void prep_kernel(
    const float* __restrict__ W1, const float* __restrict__ b1,
    short* __restrict__ w1f)
{
    const int fid  = blockIdx.x * 256 + threadIdx.x;  // 0..3071
    const int mt   = fid / 192;
    const int rem  = fid % 192;
    const int t    = rem >> 6;
    const int lane = rem & 63;
    const int row  = mt * 16 + (lane & 15);
    const int k0   = t * 32 + (lane >> 4) * 8;
    bf16x8 v;
#pragma unroll
    for (int j = 0; j < 8; ++j) {
        const int k = k0 + j;
        float val = 0.f;
        if (k < K_IN)       val = W1[row * K_IN + k];
        else if (k == K_IN) val = b1[row];
        v[j] = f2bf(val);
    }
    *(bf16x8*)&w1f[(size_t)fid * 8] = v;
}

// ---------------------------------------------------------------------------
// fused: per (b, 64-pixel tile): stage x (3 refs) -> MFMA f1 -> relu -> W3 dot
// -> sigmoid -> normalize over refs -> write w, and z = sum_ref w*d from the
// bf16 LDS copy.  data is read exactly once.
// MFMA 16x16x32 bf16; A/B frags contiguous-8-per-lane; C col=lane&15,
// row=(lane>>4)*4+r (HW-verified layouts, same as the R1 kernel that passed).
// ---------------------------------------------------------------------------
__global__ __launch_bounds__(256) void fused_kernel(
    const float* __restrict__ data, const float* __restrict__ gt,
    const short* __restrict__ w1f, const float* __restrict__ W3,
    const float* __restrict__ b3, float* __restrict__ out)
{
    __shared__ short xls[NR * NKB * P * 8];   // 36 KB  [ref][kb][px][8]
    __shared__ float p_lds[4][NR * P];        // 3 KB
    __shared__ float s_lds[NR][P];
    __shared__ float w_lds[NR][P];

    const int tid  = threadIdx.x;
    const int lane = tid & 63;
    const int wave = tid >> 6;
    const int b    = blockIdx.x >> 4;          // 0..127
    const int pt0  = (blockIdx.x & 15) * P;    // pixel tile base

    // ---- stage x = [data(64); gt(3); 1; zeros] as bf16 ----
    {
        const int px = tid & 63;
        const int gp = pt0 + px;
#pragma unroll
        for (int i = 0; i < 9; ++i) {
            const int it  = wave * 9 + i;      // 36 (ref,kb) items over 4 waves
            const int ref = it / NKB, kb = it % NKB;
            bf16x8 v;
#pragma unroll
            for (int j = 0; j < 8; ++j) {
                const int k = kb * 8 + j;
                float val = 0.f;
                if (k < CD)         val = data[((size_t)(b * NR + ref) * CD + k) * HW + gp];
                else if (k < K_IN)  val = gt[((size_t)b * CG + (k - CD)) * HW + gp];
                else if (k == K_IN) val = 1.0f;
                v[j] = f2bf(val);
            }
            *(bf16x8*)&xls[((ref * NKB + kb) * P + px) * 8] = v;
        }
    }

    // ---- per-wave A-frags (64 hidden ch) + W3 values ----
    const int col = lane & 15, kq = lane >> 4;
    bf16x8 afrag[4][3];
#pragma unroll
    for (int i = 0; i < 4; ++i)
#pragma unroll
        for (int t = 0; t < 3; ++t)
            afrag[i][t] = *(const bf16x8*)&w1f[(((size_t)(wave * 4 + i) * 3 + t) * 64 + lane) * 8];
    float w3v[4][4];
#pragma unroll
    for (int i = 0; i < 4; ++i)
#pragma unroll
        for (int r = 0; r < 4; ++r)
            w3v[i][r] = W3[wave * 64 + i * 16 + kq * 4 + r];

    __syncthreads();

    // ---- 12 n-tiles (3 refs x 4 pixel sub-tiles of 16) ----
#pragma unroll
    for (int nt = 0; nt < NR * 4; ++nt) {
        const int ref = nt >> 2, pn0 = (nt & 3) * 16;
        bf16x8 bfrag[3];
#pragma unroll
        for (int t = 0; t < 3; ++t)
            bfrag[t] = *(const bf16x8*)&xls[((ref * NKB + t * 4 + kq) * P + pn0 + col) * 8];

        f32x4 acc[4];
#pragma unroll
        for (int i = 0; i < 4; ++i) acc[i] = (f32x4){0.f, 0.f, 0.f, 0.f};
#pragma unroll
        for (int t = 0; t < 3; ++t)
#pragma unroll
            for (int i = 0; i < 4; ++i)
                acc[i] = __builtin_amdgcn_mfma_f32_16x16x32_bf16(
                    afrag[i][t], bfrag[t], acc[i], 0, 0, 0);

        float partial = 0.f;
#pragma unroll
        for (int i = 0; i < 4; ++i)
#pragma unroll
            for (int r = 0; r < 4; ++r)
                partial += w3v[i][r] * fmaxf(acc[i][r], 0.f);
        partial += __shfl_xor(partial, 16);   // sum over kq groups
        partial += __shfl_xor(partial, 32);
        if (lane < 16) p_lds[wave][ref * P + pn0 + lane] = partial;
    }
    __syncthreads();

    // ---- cross-wave sum + bias -> sigmoid ----
    if (tid < NR * P) {
        const float t = p_lds[0][tid] + p_lds[1][tid] + p_lds[2][tid]
                      + p_lds[3][tid] + b3[0];
        s_lds[tid >> 6][tid & 63] = 1.f / (1.f + __expf(-t));
    }
    __syncthreads();

    // ---- normalize over refs; write w ----
    float* wout = out + (size_t)BS * CD * HW;
    if (tid < P) {
        const float s0 = s_lds[0][tid], s1 = s_lds[1][tid], s2 = s_lds[2][tid];
        const float inv = 1.f / (s0 + s1 + s2);
        const float w0 = s0 * inv, w1 = s1 * inv, w2 = s2 * inv;
        w_lds[0][tid] = w0; w_lds[1][tid] = w1; w_lds[2][tid] = w2;
        wout[((size_t)b * NR + 0) * HW + pt0 + tid] = w0;
        wout[((size_t)b * NR + 1) * HW + pt0 + tid] = w1;
        wout[((size_t)b * NR + 2) * HW + pt0 + tid] = w2;
    }
    __syncthreads();

    // ---- z = sum_ref w * d  (d from bf16 LDS copy; data never re-read) ----
    {
        const int px = tid & 63, grp = tid >> 6;
        const float w0 = w_lds[0][px], w1 = w_lds[1][px], w2 = w_lds[2][px];
        const int gp = pt0 + px;
#pragma unroll
        for (int q = 0; q < 2; ++q) {
            const int kb = grp * 2 + q;       // data channel blocks 0..7
            const bf16x8 v0 = *(const bf16x8*)&xls[((0 * NKB + kb) * P + px) * 8];
            const bf16x8 v1 = *(const bf16x8*)&xls[((1 * NKB + kb) * P + px) * 8];
            const bf16x8 v2 = *(const bf16x8*)&xls[((2 * NKB + kb) * P + px) * 8];
#pragma unroll
            for (int j = 0; j < 8; ++j) {
                const float z = w0 * bf2f(v0[j]) + w1 * bf2f(v1[j]) + w2 * bf2f(v2[j]);
                out[((size_t)b * CD + kb * 8 + j) * HW + gp] = z;
            }
        }
    }
}

extern "C" void kernel_launch(void* const* d_in, const int* in_sizes, int n_in,
                              void* d_out, int out_size, void* d_ws, size_t ws_size,
                              hipStream_t stream)
{
    const float* data = (const float*)d_in[0];
    const float* gt   = (const float*)d_in[1];
    const float* W1   = (const float*)d_in[2];
    const float* b1   = (const float*)d_in[3];
    const float* W3   = (const float*)d_in[4];
    const float* b3   = (const float*)d_in[5];
    float* out  = (float*)d_out;
    short* w1f  = (short*)d_ws;   // 3072*8 bf16 = 49 KB fragment-ordered W1

    prep_kernel<<<12, 256, 0, stream>>>(W1, b1, w1f);
    fused_kernel<<<BS * (HW / P), 256, 0, stream>>>(data, gt, w1f, W3, b3, out);
}

// Round 4
// 174.289 us; speedup vs baseline: 2.5126x; 1.2415x over previous
//
#include <hip/hip_runtime.h>
#include <hip/hip_bf16.h>

#define BS 128
#define NR 3
#define CD 64
#define CG 3
#define CH 256
#define HW 1024   // 32*32
#define K_IN 67   // CD + CG; k==67 is the folded-bias constant-1 column
#define P 64      // pixels per block

typedef __attribute__((ext_vector_type(4))) short bf16x4;
typedef __attribute__((ext_vector_type(8))) short bf16x8;
typedef __attribute__((ext_vector_type(4))) float f32x4;

static __device__ __forceinline__ short f2bf(float x) {
    union { __hip_bfloat16 b; short s; } c;
    c.b = __float2bfloat16(x);
    return c.s;
}
static __device__ __forceinline__ float bf2f(short s) {
    union { unsigned u; float f; } c;
    c.u = (unsigned)(unsigned short)s << 16;
    return c.f;
}

// ---------------------------------------------------------------------------
// prep: pack W1 (b1 folded at k=67) into MFMA-A fragment order, bf16.
// w1f[((mt*3 + t)*64 + lane)*8 + j]: A row = mt*16+(lane&15),
// k = t*32 + (lane>>4)*8 + j.  49 KB into d_ws. (unchanged from R3 - verified)
// ---------------------------------------------------------------------------
__global__ __launch_bounds__(256) void prep_kernel(
    const float* __restrict__ W1, const float* __restrict__ b1,
    short* __restrict__ w1f)
{
    const int fid  = blockIdx.x * 256 + threadIdx.x;  // 0..3071
    const int mt   = fid / 192;
    const int rem  = fid % 192;
    const int t    = rem >> 6;
    const int lane = rem & 63;
    const int row  = mt * 16 + (lane & 15);
    const int k0   = t * 32 + (lane >> 4) * 8;
    bf16x8 v;
#pragma unroll
    for (int j = 0; j < 8; ++j) {
        const int k = k0 + j;
        float val = 0.f;
        if (k < K_IN)       val = W1[row * K_IN + k];
        else if (k == K_IN) val = b1[row];
        v[j] = f2bf(val);
    }
    *(bf16x8*)&w1f[(size_t)fid * 8] = v;
}

// ---------------------------------------------------------------------------
// fused kernel.  LDS x-layout: 8B chunks  xls[(ref*16 + c2)*P + px][4]
// where chunk c2 holds channels 4*c2..4*c2+3 for one pixel.
// k=64..95 region shared across refs: gtp page (g0,g1,g2,1) + zero page.
// ---------------------------------------------------------------------------
__global__ __launch_bounds__(256, 4) void fused_kernel(
    const float* __restrict__ data, const float* __restrict__ gt,
    const short* __restrict__ w1f, const float* __restrict__ W3,
    const float* __restrict__ b3, float* __restrict__ out)
{
    __shared__ short xls[NR * 16 * P * 4];  // 24576 B
    __shared__ short gtp[P * 4];            // 512 B: (g0,g1,g2,1) per px
    __shared__ short zp[P * 4];             // 512 B zeros
    __shared__ float p_lds[4][NR * P];      // 3 KB
    __shared__ float s_lds[NR][P];
    __shared__ float w_lds[NR][P];

    const int tid  = threadIdx.x;
    const int lane = tid & 63;
    const int wave = tid >> 6;
    const int b    = blockIdx.x >> 4;          // 0..127
    const int pt0  = (blockIdx.x & 15) * P;    // pixel tile base
    const int col  = lane & 15, kq = lane >> 4;

    // ---- A-frags + W3 (issue global loads early; overlap with staging) ----
    bf16x8 afrag[4][3];
#pragma unroll
    for (int i = 0; i < 4; ++i)
#pragma unroll
        for (int t = 0; t < 3; ++t)
            afrag[i][t] = *(const bf16x8*)&w1f[(((size_t)(wave * 4 + i) * 3 + t) * 64 + lane) * 8];
    float w3v[4][4];
#pragma unroll
    for (int i = 0; i < 4; ++i)
#pragma unroll
        for (int r = 0; r < 4; ++r)
            w3v[i][r] = W3[wave * 64 + i * 16 + kq * 4 + r];

    // ---- zero page + gt page ----
    if (tid < P) *(bf16x4*)&zp[tid * 4] = (bf16x4){0, 0, 0, 0};
    {
        const int c = tid >> 6, px = tid & 63;
        if (c < CG) gtp[px * 4 + c] = f2bf(gt[((size_t)b * CG + c) * HW + pt0 + px]);
        else        gtp[px * 4 + 3] = (short)0x3F80;   // 1.0 bf16 (bias column)
    }

    // ---- data staging: 12 float4 loads/thread, bf16 scatter to LDS ----
#pragma unroll
    for (int half = 0; half < 2; ++half) {
        float4 ld[6];
#pragma unroll
        for (int u = 0; u < 6; ++u) {
            const int q = (half * 6 + u) * 256 + tid;
            const int ref = q >> 10, ch = (q >> 4) & 63, p4 = q & 15;
            ld[u] = *(const float4*)(data + ((size_t)(b * NR + ref) * CD + ch) * HW + pt0 + 4 * p4);
        }
#pragma unroll
        for (int u = 0; u < 6; ++u) {
            const int q = (half * 6 + u) * 256 + tid;
            const int ref = q >> 10, ch = (q >> 4) & 63, p4 = q & 15;
            short* xp = &xls[((ref * 16 + (ch >> 2)) * P + 4 * p4) * 4 + (ch & 3)];
            xp[0]  = f2bf(ld[u].x);
            xp[4]  = f2bf(ld[u].y);
            xp[8]  = f2bf(ld[u].z);
            xp[12] = f2bf(ld[u].w);
        }
    }

    __syncthreads();

    // ---- MFMA: 12 n-tiles (3 refs x 4 pixel sub-tiles of 16) ----
#pragma unroll
    for (int nt = 0; nt < NR * 4; ++nt) {
        const int ref = nt >> 2, pn0 = (nt & 3) * 16;
        bf16x8 bfrag[3];
#pragma unroll
        for (int t = 0; t < 3; ++t) {
            const short* plo;
            const short* phi;
            if (t < 2) {
                const int c2 = t * 8 + kq * 2;
                plo = &xls[((ref * 16 + c2)     * P) * 4];
                phi = &xls[((ref * 16 + c2 + 1) * P) * 4];
            } else {                       // k = 64..95: shared gt/zero pages
                plo = (kq == 0) ? gtp : zp;
                phi = zp;
            }
            const bf16x4 lo = *(const bf16x4*)&plo[(pn0 + col) * 4];
            const bf16x4 hi = *(const bf16x4*)&phi[(pn0 + col) * 4];
            bfrag[t] = __builtin_shufflevector(lo, hi, 0, 1, 2, 3, 4, 5, 6, 7);
        }

        f32x4 acc[4];
#pragma unroll
        for (int i = 0; i < 4; ++i) acc[i] = (f32x4){0.f, 0.f, 0.f, 0.f};
#pragma unroll
        for (int t = 0; t < 3; ++t)
#pragma unroll
            for (int i = 0; i < 4; ++i)
                acc[i] = __builtin_amdgcn_mfma_f32_16x16x32_bf16(
                    afrag[i][t], bfrag[t], acc[i], 0, 0, 0);

        float partial = 0.f;
#pragma unroll
        for (int i = 0; i < 4; ++i)
#pragma unroll
            for (int r = 0; r < 4; ++r)
                partial += w3v[i][r] * fmaxf(acc[i][r], 0.f);
        partial += __shfl_xor(partial, 16);
        partial += __shfl_xor(partial, 32);
        if (lane < 16) p_lds[wave][ref * P + pn0 + lane] = partial;
    }
    __syncthreads();

    // ---- cross-wave sum + bias -> sigmoid ----
    if (tid < NR * P) {
        const float t = p_lds[0][tid] + p_lds[1][tid] + p_lds[2][tid]
                      + p_lds[3][tid] + b3[0];
        s_lds[tid >> 6][tid & 63] = 1.f / (1.f + __expf(-t));
    }
    __syncthreads();

    // ---- normalize over refs; write w ----
    float* wout = out + (size_t)BS * CD * HW;
    if (tid < P) {
        const float s0 = s_lds[0][tid], s1 = s_lds[1][tid], s2 = s_lds[2][tid];
        const float inv = 1.f / (s0 + s1 + s2);
        const float w0 = s0 * inv, w1 = s1 * inv, w2 = s2 * inv;
        w_lds[0][tid] = w0; w_lds[1][tid] = w1; w_lds[2][tid] = w2;
        wout[((size_t)b * NR + 0) * HW + pt0 + tid] = w0;
        wout[((size_t)b * NR + 1) * HW + pt0 + tid] = w1;
        wout[((size_t)b * NR + 2) * HW + pt0 + tid] = w2;
    }
    __syncthreads();

    // ---- z = sum_ref w * d  (bf16 LDS copy; float4 stores) ----
#pragma unroll
    for (int u = 0; u < 4; ++u) {
        const int q = u * 256 + tid;
        const int ch = q >> 4, p4 = q & 15;
        float zx = 0.f, zy = 0.f, zz = 0.f, zw = 0.f;
#pragma unroll
        for (int ref = 0; ref < NR; ++ref) {
            const float4 wv = *(const float4*)&w_lds[ref][4 * p4];
            const short* xp = &xls[((ref * 16 + (ch >> 2)) * P + 4 * p4) * 4 + (ch & 3)];
            zx += wv.x * bf2f(xp[0]);
            zy += wv.y * bf2f(xp[4]);
            zz += wv.z * bf2f(xp[8]);
            zw += wv.w * bf2f(xp[12]);
        }
        const float4 zv = {zx, zy, zz, zw};
        *(float4*)(out + ((size_t)b * CD + ch) * HW + pt0 + 4 * p4) = zv;
    }
}

extern "C" void kernel_launch(void* const* d_in, const int* in_sizes, int n_in,
                              void* d_out, int out_size, void* d_ws, size_t ws_size,
                              hipStream_t stream)
{
    const float* data = (const float*)d_in[0];
    const float* gt   = (const float*)d_in[1];
    const float* W1   = (const float*)d_in[2];
    const float* b1   = (const float*)d_in[3];
    const float* W3   = (const float*)d_in[4];
    const float* b3   = (const float*)d_in[5];
    float* out  = (float*)d_out;
    short* w1f  = (short*)d_ws;   // 3072*8 bf16 = 49 KB fragment-ordered W1

    prep_kernel<<<12, 256, 0, stream>>>(W1, b1, w1f);
    fused_kernel<<<BS * (HW / P), 256, 0, stream>>>(data, gt, w1f, W3, b3, out);
}